// Round 1
// baseline (169.051 us; speedup 1.0000x reference)
//
#include <hip/hip_runtime.h>

// Problem: B=8,H=8,S=1024,D=64 fp32 attention with raw-exp softmax,
// multiplicative key mask, outputs (context[8,8,1024,64], scores[8,8,1024,1024]).
// Memory-bound on the 268 MB scores write -> f16 MFMA for all matmuls,
// no LDS staging (K/V are L2-resident per (b,h)).

typedef float      f32x4 __attribute__((ext_vector_type(4)));
typedef _Float16   f16x8 __attribute__((ext_vector_type(8)));
typedef _Float16   f16x4 __attribute__((ext_vector_type(4)));

#define MFMA_16x16x32(A, B, C) __builtin_amdgcn_mfma_f32_16x16x32_f16((A), (B), (C), 0, 0, 0)
#define MFMA_16x16x16(A, B, C) __builtin_amdgcn_mfma_f32_16x16x16f16((A), (B), (C), 0, 0, 0)

#define BHN 64      // B*H
#define SEQ 1024
#define DIM 64

__device__ inline f16x8 cvt8(f32x4 a, f32x4 b) {
    f16x8 r;
    r[0] = (_Float16)a[0]; r[1] = (_Float16)a[1]; r[2] = (_Float16)a[2]; r[3] = (_Float16)a[3];
    r[4] = (_Float16)b[0]; r[5] = (_Float16)b[1]; r[6] = (_Float16)b[2]; r[7] = (_Float16)b[3];
    return r;
}

// Pre-pass: K -> f16 same layout; V -> f16 transposed per (b,h): VT[bh][d][key].
// Grid: 64 bh * 8 key-chunks of 128. Block 256.
__global__ __launch_bounds__(256)
void cvt_kv(const float* __restrict__ K, const float* __restrict__ V,
            _Float16* __restrict__ Kh, _Float16* __restrict__ VT)
{
    __shared__ _Float16 tile[128 * 65];   // +1 f16 pad breaks bank alignment
    const int bh = blockIdx.x >> 3;
    const int kc = blockIdx.x & 7;
    const int t  = threadIdx.x;
    const size_t base = ((size_t)bh * SEQ + (size_t)kc * 128) * DIM;

    for (int it = 0; it < 8; ++it) {
        int idx = it * 256 + t;          // over 128 keys x 16 float4-chunks
        int key = idx >> 4;
        int c4  = idx & 15;
        f32x4 kv = *(const f32x4*)(K + base + key * DIM + c4 * 4);
        f32x4 vv = *(const f32x4*)(V + base + key * DIM + c4 * 4);
        f16x4 kh;
        kh[0] = (_Float16)kv[0]; kh[1] = (_Float16)kv[1];
        kh[2] = (_Float16)kv[2]; kh[3] = (_Float16)kv[3];
        *(f16x4*)(Kh + base + key * DIM + c4 * 4) = kh;
        tile[key * 65 + c4 * 4 + 0] = (_Float16)vv[0];
        tile[key * 65 + c4 * 4 + 1] = (_Float16)vv[1];
        tile[key * 65 + c4 * 4 + 2] = (_Float16)vv[2];
        tile[key * 65 + c4 * 4 + 3] = (_Float16)vv[3];
    }
    __syncthreads();
    for (int it = 0; it < 4; ++it) {
        int idx = it * 256 + t;          // over 64 d-rows x 16 key-groups(8)
        int dd = idx >> 4;
        int kg = idx & 15;
        f16x8 o;
        #pragma unroll
        for (int j = 0; j < 8; ++j) o[j] = tile[(kg * 8 + j) * 65 + dd];
        *(f16x8*)(VT + ((size_t)bh * DIM + dd) * SEQ + (size_t)kc * 128 + kg * 8) = o;
    }
}

// Main kernel. Grid 512 blocks x 256 thr. Wave w owns 32 q-rows (2 sub-tiles of 16).
// Swapped QK^T: acc = mfma(A=K, B=Q) -> acc[key_local][qrow_local]:
//   lane: qrow = lane&15, keys = (lane>>4)*4 + i.
// PV as ctx^T: mfma(A=VT, B=P^T) -> acc[d_local][qrow_local]; P^T frag == QK acc layout.
template <bool PRECONV>
__global__ __launch_bounds__(256)
void attn_main(const float* __restrict__ Q, const float* __restrict__ K,
               const float* __restrict__ V, const float* __restrict__ mask,
               const _Float16* __restrict__ Kh, const _Float16* __restrict__ VT,
               float* __restrict__ ctx, float* __restrict__ scores)
{
    const int bid = blockIdx.x;
    // XCD-bijective swizzle (512 % 8 == 0): each XCD gets 8 whole (b,h) panels.
    const int wg  = ((bid & 7) << 6) | (bid >> 3);
    const int bh  = wg >> 3;
    const int qb  = wg & 7;
    const int b   = bh >> 3;
    const int w    = threadIdx.x >> 6;
    const int lane = threadIdx.x & 63;
    const int col  = lane & 15;    // qrow-local (QK) / d-local (PV)
    const int g    = lane >> 4;
    const int q0   = qb * 128 + w * 32;
    const float scale = 0.125f;   // 1/sqrt(64)

    // ---- Q fragments: qf[sub][frag] : Q[q0+sub*16+col][frag*32 + g*8 .. +7]
    f16x8 qf[2][2];
    {
        const float* qbase = Q + ((size_t)bh * SEQ + q0) * DIM;
        #pragma unroll
        for (int s = 0; s < 2; ++s)
            #pragma unroll
            for (int f = 0; f < 2; ++f) {
                const float* p = qbase + (s * 16 + col) * DIM + f * 32 + g * 8;
                qf[s][f] = cvt8(*(const f32x4*)p, *(const f32x4*)(p + 4));
            }
    }
    const float* mb = mask + (size_t)b * SEQ;

    // ---- pass 1: row sums of exp(s)*mask
    float rsum[2] = {0.f, 0.f};
    for (int kt = 0; kt < 64; ++kt) {
        f16x8 kf0, kf1;
        if (PRECONV) {
            const _Float16* kp = Kh + ((size_t)bh * SEQ + kt * 16 + col) * DIM + g * 8;
            kf0 = *(const f16x8*)kp;
            kf1 = *(const f16x8*)(kp + 32);
        } else {
            const float* kp = K + ((size_t)bh * SEQ + kt * 16 + col) * DIM + g * 8;
            kf0 = cvt8(*(const f32x4*)kp,        *(const f32x4*)(kp + 4));
            kf1 = cvt8(*(const f32x4*)(kp + 32), *(const f32x4*)(kp + 36));
        }
        f32x4 m4 = *(const f32x4*)(mb + kt * 16 + g * 4);
        #pragma unroll
        for (int s = 0; s < 2; ++s) {
            f32x4 acc = {0.f, 0.f, 0.f, 0.f};
            acc = MFMA_16x16x32(kf0, qf[s][0], acc);
            acc = MFMA_16x16x32(kf1, qf[s][1], acc);
            rsum[s] += __expf(acc[0] * scale) * m4[0] + __expf(acc[1] * scale) * m4[1]
                     + __expf(acc[2] * scale) * m4[2] + __expf(acc[3] * scale) * m4[3];
        }
    }
    float inv[2];
    #pragma unroll
    for (int s = 0; s < 2; ++s) {
        float r = rsum[s];
        r += __shfl_xor(r, 16, 64);   // sum the 4 lane-groups (same qrow=col)
        r += __shfl_xor(r, 32, 64);
        inv[s] = 1.0f / (r + 1e-8f);
    }

    // ---- pass 2: recompute, normalize, write scores, accumulate PV (ctx^T)
    f32x4 cacc[2][4];
    #pragma unroll
    for (int s = 0; s < 2; ++s)
        #pragma unroll
        for (int dt = 0; dt < 4; ++dt) cacc[s][dt] = (f32x4){0.f, 0.f, 0.f, 0.f};

    float* srow0 = scores + ((size_t)bh * SEQ + q0) * SEQ;

    for (int kt = 0; kt < 64; ++kt) {
        f16x8 kf0, kf1;
        if (PRECONV) {
            const _Float16* kp = Kh + ((size_t)bh * SEQ + kt * 16 + col) * DIM + g * 8;
            kf0 = *(const f16x8*)kp;
            kf1 = *(const f16x8*)(kp + 32);
        } else {
            const float* kp = K + ((size_t)bh * SEQ + kt * 16 + col) * DIM + g * 8;
            kf0 = cvt8(*(const f32x4*)kp,        *(const f32x4*)(kp + 4));
            kf1 = cvt8(*(const f32x4*)(kp + 32), *(const f32x4*)(kp + 36));
        }
        f32x4 m4 = *(const f32x4*)(mb + kt * 16 + g * 4);

        f16x4 pf[2];
        #pragma unroll
        for (int s = 0; s < 2; ++s) {
            f32x4 acc = {0.f, 0.f, 0.f, 0.f};
            acc = MFMA_16x16x32(kf0, qf[s][0], acc);
            acc = MFMA_16x16x32(kf1, qf[s][1], acc);
            f32x4 p;
            p[0] = __expf(acc[0] * scale) * m4[0] * inv[s];
            p[1] = __expf(acc[1] * scale) * m4[1] * inv[s];
            p[2] = __expf(acc[2] * scale) * m4[2] * inv[s];
            p[3] = __expf(acc[3] * scale) * m4[3] * inv[s];
            // lane writes scores[q0+s*16+col][kt*16+g*4 .. +3] : contiguous 16 B
            *(f32x4*)(srow0 + ((size_t)(s * 16 + col)) * SEQ + kt * 16 + g * 4) = p;
            f16x4 ph;
            ph[0] = (_Float16)p[0]; ph[1] = (_Float16)p[1];
            ph[2] = (_Float16)p[2]; ph[3] = (_Float16)p[3];
            pf[s] = ph;
        }
        #pragma unroll
        for (int dt = 0; dt < 4; ++dt) {
            f16x4 vt;
            if (PRECONV) {
                // VT[bh][dt*16+col][kt*16 + g*4 .. +3] : contiguous 8 B
                vt = *(const f16x4*)(VT + ((size_t)bh * DIM + dt * 16 + col) * SEQ + kt * 16 + g * 4);
            } else {
                #pragma unroll
                for (int i = 0; i < 4; ++i)
                    vt[i] = (_Float16)V[((size_t)bh * SEQ + kt * 16 + g * 4 + i) * DIM + dt * 16 + col];
            }
            cacc[0][dt] = MFMA_16x16x16(vt, pf[0], cacc[0][dt]);
            cacc[1][dt] = MFMA_16x16x16(vt, pf[1], cacc[1][dt]);
        }
    }

    // ---- context write: lane holds ctx[q0+s*16+col][dt*16 + g*4 .. +3]
    #pragma unroll
    for (int s = 0; s < 2; ++s)
        #pragma unroll
        for (int dt = 0; dt < 4; ++dt)
            *(f32x4*)(ctx + ((size_t)bh * SEQ + q0 + s * 16 + col) * DIM + dt * 16 + g * 4)
                = cacc[s][dt];
}

extern "C" void kernel_launch(void* const* d_in, const int* in_sizes, int n_in,
                              void* d_out, int out_size, void* d_ws, size_t ws_size,
                              hipStream_t stream)
{
    const float* Q    = (const float*)d_in[0];
    const float* K    = (const float*)d_in[1];
    const float* V    = (const float*)d_in[2];
    const float* mask = (const float*)d_in[3];
    float* ctx    = (float*)d_out;
    float* scores = ctx + (size_t)BHN * SEQ * DIM;   // context first, then scores

    const size_t elems = (size_t)BHN * SEQ * DIM;    // 4,194,304
    const size_t need  = elems * 2 * sizeof(_Float16);  // Kh + VT = 16 MB
    if (ws_size >= need) {
        _Float16* Kh = (_Float16*)d_ws;
        _Float16* VT = Kh + elems;
        cvt_kv<<<512, 256, 0, stream>>>(K, V, Kh, VT);
        attn_main<true><<<512, 256, 0, stream>>>(Q, K, V, mask, Kh, VT, ctx, scores);
    } else {
        attn_main<false><<<512, 256, 0, stream>>>(Q, K, V, mask, nullptr, nullptr, ctx, scores);
    }
}

// Round 2
// 159.811 us; speedup vs baseline: 1.0578x; 1.0578x over previous
//
#include <hip/hip_runtime.h>

// B=8,H=8,S=1024,D=64 fp32 attention, raw-exp softmax, multiplicative key mask.
// Outputs: context[64,1024,64] then scores[64,1024,1024], both fp32.
// Memory-bound on the 268 MB scores write. f16 MFMA for all matmuls.
// R2: key-split wave pairs (4096 waves = 4/SIMD) + register prefetch.

typedef float      f32x4 __attribute__((ext_vector_type(4)));
typedef _Float16   f16x8 __attribute__((ext_vector_type(8)));
typedef _Float16   f16x4 __attribute__((ext_vector_type(4)));

#define MFMA32(A, B, C) __builtin_amdgcn_mfma_f32_16x16x32_f16((A), (B), (C), 0, 0, 0)
#define MFMA16(A, B, C) __builtin_amdgcn_mfma_f32_16x16x16f16((A), (B), (C), 0, 0, 0)

#define BHN 64
#define SEQ 1024
#define DIM 64

__device__ inline f16x8 cvt8(f32x4 a, f32x4 b) {
    f16x8 r;
    r[0] = (_Float16)a[0]; r[1] = (_Float16)a[1]; r[2] = (_Float16)a[2]; r[3] = (_Float16)a[3];
    r[4] = (_Float16)b[0]; r[5] = (_Float16)b[1]; r[6] = (_Float16)b[2]; r[7] = (_Float16)b[3];
    return r;
}

// Pre-pass: K -> f16 same layout; V -> f16 transposed per (b,h): VT[bh][d][key].
__global__ __launch_bounds__(256)
void cvt_kv(const float* __restrict__ K, const float* __restrict__ V,
            _Float16* __restrict__ Kh, _Float16* __restrict__ VT)
{
    __shared__ _Float16 tile[128 * 65];
    const int bh = blockIdx.x >> 3;
    const int kc = blockIdx.x & 7;
    const int t  = threadIdx.x;
    const size_t base = ((size_t)bh * SEQ + (size_t)kc * 128) * DIM;

    for (int it = 0; it < 8; ++it) {
        int idx = it * 256 + t;
        int key = idx >> 4;
        int c4  = idx & 15;
        f32x4 kv = *(const f32x4*)(K + base + key * DIM + c4 * 4);
        f32x4 vv = *(const f32x4*)(V + base + key * DIM + c4 * 4);
        f16x4 kh4;
        kh4[0] = (_Float16)kv[0]; kh4[1] = (_Float16)kv[1];
        kh4[2] = (_Float16)kv[2]; kh4[3] = (_Float16)kv[3];
        *(f16x4*)(Kh + base + key * DIM + c4 * 4) = kh4;
        tile[key * 65 + c4 * 4 + 0] = (_Float16)vv[0];
        tile[key * 65 + c4 * 4 + 1] = (_Float16)vv[1];
        tile[key * 65 + c4 * 4 + 2] = (_Float16)vv[2];
        tile[key * 65 + c4 * 4 + 3] = (_Float16)vv[3];
    }
    __syncthreads();
    for (int it = 0; it < 4; ++it) {
        int idx = it * 256 + t;
        int dd = idx >> 4;
        int kg = idx & 15;
        f16x8 o;
        #pragma unroll
        for (int j = 0; j < 8; ++j) o[j] = tile[(kg * 8 + j) * 65 + dd];
        *(f16x8*)(VT + ((size_t)bh * DIM + dd) * SEQ + (size_t)kc * 128 + kg * 8) = o;
    }
}

// Main kernel. 1024 blocks x 256 thr (4 waves). Block covers 64 q-rows of one (b,h).
// Wave w: q sub-tile pq=w>>1 (32 rows), key half kh=w&1 (512 keys).
// Swapped QK^T: acc = mfma(A=K, B=Q) -> lane: qrow = lane&15, keys = (lane>>4)*4+i.
// PV as ctx^T via mfma(A=VT, B=P^T); cross-wave PV combine through LDS.
template <bool PRECONV>
__global__ __launch_bounds__(256, 4)
void attn_main(const float* __restrict__ Q, const float* __restrict__ K,
               const float* __restrict__ V, const float* __restrict__ mask,
               const _Float16* __restrict__ Kh, const _Float16* __restrict__ VT,
               float* __restrict__ ctx, float* __restrict__ scores)
{
    __shared__ float rs_lds[4][2][16];
    __shared__ float cbuf[2][32][64];    // [pair][elem][lane] — conflict-free

    const int bid = blockIdx.x;
    // XCD-bijective swizzle (1024 % 8 == 0): XCD x gets bh in [x*8, x*8+8).
    const int wg  = ((bid & 7) << 7) | (bid >> 3);
    const int bh  = wg >> 4;
    const int qb  = wg & 15;
    const int b   = bh >> 3;
    const int w    = threadIdx.x >> 6;
    const int lane = threadIdx.x & 63;
    const int col  = lane & 15;
    const int g    = lane >> 4;
    const int pq   = w >> 1;           // q sub-tile (32 rows)
    const int khf  = w & 1;            // key half
    const int q0   = qb * 64 + pq * 32;
    const int kb   = khf * 512;
    const float scale = 0.125f;

    // ---- Q fragments: qf[s][f] : Q[q0+s*16+col][f*32 + g*8 .. +7]
    f16x8 qf[2][2];
    {
        const float* qbase = Q + ((size_t)bh * SEQ + q0) * DIM;
        #pragma unroll
        for (int s = 0; s < 2; ++s)
            #pragma unroll
            for (int f = 0; f < 2; ++f) {
                const float* p = qbase + (s * 16 + col) * DIM + f * 32 + g * 8;
                qf[s][f] = cvt8(*(const f32x4*)p, *(const f32x4*)(p + 4));
            }
    }
    const float* mb = mask + (size_t)b * SEQ + kb;

    auto loadK = [&](int kt, f16x8& a, f16x8& c) {
        if (PRECONV) {
            const _Float16* kp = Kh + ((size_t)bh * SEQ + kb + kt * 16 + col) * DIM + g * 8;
            a = *(const f16x8*)kp;
            c = *(const f16x8*)(kp + 32);
        } else {
            const float* kp = K + ((size_t)bh * SEQ + kb + kt * 16 + col) * DIM + g * 8;
            a = cvt8(*(const f32x4*)kp,        *(const f32x4*)(kp + 4));
            c = cvt8(*(const f32x4*)(kp + 32), *(const f32x4*)(kp + 36));
        }
    };

    // ---- pass 1: partial row sums of exp(s)*mask over this wave's 512 keys
    float rsum[2] = {0.f, 0.f};
    {
        f16x8 k0, k1;
        loadK(0, k0, k1);
        f32x4 m4 = *(const f32x4*)(mb + g * 4);
        for (int kt = 0; kt < 32; ++kt) {
            int ktn = (kt + 1) & 31;
            f16x8 n0, n1;
            loadK(ktn, n0, n1);
            f32x4 nm = *(const f32x4*)(mb + ktn * 16 + g * 4);
            #pragma unroll
            for (int s = 0; s < 2; ++s) {
                f32x4 acc = {0.f, 0.f, 0.f, 0.f};
                acc = MFMA32(k0, qf[s][0], acc);
                acc = MFMA32(k1, qf[s][1], acc);
                rsum[s] += __expf(acc[0] * scale) * m4[0] + __expf(acc[1] * scale) * m4[1]
                         + __expf(acc[2] * scale) * m4[2] + __expf(acc[3] * scale) * m4[3];
            }
            k0 = n0; k1 = n1; m4 = nm;
        }
    }
    #pragma unroll
    for (int s = 0; s < 2; ++s) {
        float r = rsum[s];
        r += __shfl_xor(r, 16, 64);
        r += __shfl_xor(r, 32, 64);
        rsum[s] = r;
    }
    if (g == 0) {
        rs_lds[w][0][col] = rsum[0];
        rs_lds[w][1][col] = rsum[1];
    }
    __syncthreads();
    float inv[2];
    #pragma unroll
    for (int s = 0; s < 2; ++s)
        inv[s] = 1.0f / (rs_lds[pq * 2][s][col] + rs_lds[pq * 2 + 1][s][col] + 1e-8f);

    // ---- pass 2: recompute, normalize, write scores, accumulate partial PV
    f32x4 cacc[2][4];
    #pragma unroll
    for (int s = 0; s < 2; ++s)
        #pragma unroll
        for (int dt = 0; dt < 4; ++dt) cacc[s][dt] = (f32x4){0.f, 0.f, 0.f, 0.f};

    float* srow0 = scores + ((size_t)bh * SEQ + q0) * SEQ + kb;
    const _Float16* vtb = VT + (size_t)bh * DIM * SEQ + kb;

    {
        f16x8 k0, k1;
        loadK(0, k0, k1);
        f32x4 m4 = *(const f32x4*)(mb + g * 4);
        for (int kt = 0; kt < 32; ++kt) {
            int ktn = (kt + 1) & 31;
            f16x8 n0, n1;
            loadK(ktn, n0, n1);
            f32x4 nm = *(const f32x4*)(mb + ktn * 16 + g * 4);

            f16x4 pf[2];
            #pragma unroll
            for (int s = 0; s < 2; ++s) {
                f32x4 acc = {0.f, 0.f, 0.f, 0.f};
                acc = MFMA32(k0, qf[s][0], acc);
                acc = MFMA32(k1, qf[s][1], acc);
                f32x4 p;
                p[0] = __expf(acc[0] * scale) * m4[0] * inv[s];
                p[1] = __expf(acc[1] * scale) * m4[1] * inv[s];
                p[2] = __expf(acc[2] * scale) * m4[2] * inv[s];
                p[3] = __expf(acc[3] * scale) * m4[3] * inv[s];
                *(f32x4*)(srow0 + ((size_t)(s * 16 + col)) * SEQ + kt * 16 + g * 4) = p;
                f16x4 ph;
                ph[0] = (_Float16)p[0]; ph[1] = (_Float16)p[1];
                ph[2] = (_Float16)p[2]; ph[3] = (_Float16)p[3];
                pf[s] = ph;
            }
            #pragma unroll
            for (int dt = 0; dt < 4; ++dt) {
                f16x4 vt;
                if (PRECONV) {
                    vt = *(const f16x4*)(vtb + ((size_t)(dt * 16 + col)) * SEQ + kt * 16 + g * 4);
                } else {
                    #pragma unroll
                    for (int i = 0; i < 4; ++i)
                        vt[i] = (_Float16)V[((size_t)bh * SEQ + kb + kt * 16 + g * 4 + i) * DIM + dt * 16 + col];
                }
                cacc[0][dt] = MFMA16(vt, pf[0], cacc[0][dt]);
                cacc[1][dt] = MFMA16(vt, pf[1], cacc[1][dt]);
            }
            k0 = n0; k1 = n1; m4 = nm;
        }
    }

    // ---- combine PV partials across the wave pair, store ctx
    if (khf == 1) {
        #pragma unroll
        for (int s = 0; s < 2; ++s)
            #pragma unroll
            for (int dt = 0; dt < 4; ++dt)
                #pragma unroll
                for (int j = 0; j < 4; ++j)
                    cbuf[pq][(s * 4 + dt) * 4 + j][lane] = cacc[s][dt][j];
    }
    __syncthreads();
    if (khf == 0) {
        #pragma unroll
        for (int s = 0; s < 2; ++s)
            #pragma unroll
            for (int dt = 0; dt < 4; ++dt) {
                f32x4 r = cacc[s][dt];
                #pragma unroll
                for (int j = 0; j < 4; ++j)
                    r[j] += cbuf[pq][(s * 4 + dt) * 4 + j][lane];
                *(f32x4*)(ctx + ((size_t)bh * SEQ + q0 + s * 16 + col) * DIM + dt * 16 + g * 4) = r;
            }
    }
}

extern "C" void kernel_launch(void* const* d_in, const int* in_sizes, int n_in,
                              void* d_out, int out_size, void* d_ws, size_t ws_size,
                              hipStream_t stream)
{
    const float* Q    = (const float*)d_in[0];
    const float* K    = (const float*)d_in[1];
    const float* V    = (const float*)d_in[2];
    const float* mask = (const float*)d_in[3];
    float* ctx    = (float*)d_out;
    float* scores = ctx + (size_t)BHN * SEQ * DIM;

    const size_t elems = (size_t)BHN * SEQ * DIM;       // 4,194,304
    const size_t need  = elems * 2 * sizeof(_Float16);  // Kh + VT = 16 MB
    if (ws_size >= need) {
        _Float16* Kh = (_Float16*)d_ws;
        _Float16* VT = Kh + elems;
        cvt_kv<<<512, 256, 0, stream>>>(K, V, Kh, VT);
        attn_main<true><<<1024, 256, 0, stream>>>(Q, K, V, mask, Kh, VT, ctx, scores);
    } else {
        attn_main<false><<<1024, 256, 0, stream>>>(Q, K, V, mask, nullptr, nullptr, ctx, scores);
    }
}

// Round 3
// 158.117 us; speedup vs baseline: 1.0692x; 1.0107x over previous
//
#include <hip/hip_runtime.h>

// B=8,H=8,S=1024,D=64 fp32 attention, raw-exp softmax, multiplicative key mask.
// Outputs: context[64,1024,64] then scores[64,1024,1024], both fp32.
// R3: scores stores staged through per-wave LDS tile, flushed as full-cache-line
// wave stores (4 rows x 256 B per instr) — fixes the 64-B-segment write pattern.

typedef float      f32x4 __attribute__((ext_vector_type(4)));
typedef _Float16   f16x8 __attribute__((ext_vector_type(8)));
typedef _Float16   f16x4 __attribute__((ext_vector_type(4)));

#define MFMA32(A, B, C) __builtin_amdgcn_mfma_f32_16x16x32_f16((A), (B), (C), 0, 0, 0)
#define MFMA16(A, B, C) __builtin_amdgcn_mfma_f32_16x16x16f16((A), (B), (C), 0, 0, 0)

#define BHN 64
#define SEQ 1024
#define DIM 64

__device__ inline f16x8 cvt8(f32x4 a, f32x4 b) {
    f16x8 r;
    r[0] = (_Float16)a[0]; r[1] = (_Float16)a[1]; r[2] = (_Float16)a[2]; r[3] = (_Float16)a[3];
    r[4] = (_Float16)b[0]; r[5] = (_Float16)b[1]; r[6] = (_Float16)b[2]; r[7] = (_Float16)b[3];
    return r;
}

// Pre-pass: K -> f16 same layout; V -> f16 transposed per (b,h): VT[bh][d][key].
__global__ __launch_bounds__(256)
void cvt_kv(const float* __restrict__ K, const float* __restrict__ V,
            _Float16* __restrict__ Kh, _Float16* __restrict__ VT)
{
    __shared__ _Float16 tile[128 * 65];
    const int bh = blockIdx.x >> 3;
    const int kc = blockIdx.x & 7;
    const int t  = threadIdx.x;
    const size_t base = ((size_t)bh * SEQ + (size_t)kc * 128) * DIM;

    for (int it = 0; it < 8; ++it) {
        int idx = it * 256 + t;
        int key = idx >> 4;
        int c4  = idx & 15;
        f32x4 kv = *(const f32x4*)(K + base + key * DIM + c4 * 4);
        f32x4 vv = *(const f32x4*)(V + base + key * DIM + c4 * 4);
        f16x4 kh4;
        kh4[0] = (_Float16)kv[0]; kh4[1] = (_Float16)kv[1];
        kh4[2] = (_Float16)kv[2]; kh4[3] = (_Float16)kv[3];
        *(f16x4*)(Kh + base + key * DIM + c4 * 4) = kh4;
        tile[key * 65 + c4 * 4 + 0] = (_Float16)vv[0];
        tile[key * 65 + c4 * 4 + 1] = (_Float16)vv[1];
        tile[key * 65 + c4 * 4 + 2] = (_Float16)vv[2];
        tile[key * 65 + c4 * 4 + 3] = (_Float16)vv[3];
    }
    __syncthreads();
    for (int it = 0; it < 4; ++it) {
        int idx = it * 256 + t;
        int dd = idx >> 4;
        int kg = idx & 15;
        f16x8 o;
        #pragma unroll
        for (int j = 0; j < 8; ++j) o[j] = tile[(kg * 8 + j) * 65 + dd];
        *(f16x8*)(VT + ((size_t)bh * DIM + dd) * SEQ + (size_t)kc * 128 + kg * 8) = o;
    }
}

// Main kernel. 1024 blocks x 256 thr (4 waves). Block = 64 q-rows of one (b,h).
// Wave w: q sub-tile pq=w>>1 (32 rows), key half khf=w&1 (512 keys).
// Swapped QK^T: acc = mfma(A=K, B=Q) -> lane: qrow = lane&15, keys = (lane>>4)*4+i.
// Scores staged in per-wave LDS tile [32 rows][64 keys] f32, XOR-swizzled,
// flushed every 4 k-tiles as 4-rows x 256-B full-line wave stores.
template <bool PRECONV>
__global__ __launch_bounds__(256, 4)
void attn_main(const float* __restrict__ Q, const float* __restrict__ K,
               const float* __restrict__ V, const float* __restrict__ mask,
               const _Float16* __restrict__ Kh, const _Float16* __restrict__ VT,
               float* __restrict__ ctx, float* __restrict__ scores)
{
    // 4 per-wave tiles of 2048 floats (32 rows x 16 granules x 4). cbuf for the
    // PV cross-wave combine aliases tiles of waves 0-1 (time-disjoint, barriers).
    __shared__ float smem[4 * 2048];
    __shared__ float rs_lds[4][2][16];

    const int bid = blockIdx.x;
    const int wg  = ((bid & 7) << 7) | (bid >> 3);   // XCD-bijective (1024%8==0)
    const int bh  = wg >> 4;
    const int qb  = wg & 15;
    const int b   = bh >> 3;
    const int w    = threadIdx.x >> 6;
    const int lane = threadIdx.x & 63;
    const int col  = lane & 15;
    const int g    = lane >> 4;
    const int pq   = w >> 1;
    const int khf  = w & 1;
    const int q0   = qb * 64 + pq * 32;
    const int kb   = khf * 512;
    const float scale = 0.125f;
    float* wtile = smem + w * 2048;

    // ---- Q fragments
    f16x8 qf[2][2];
    {
        const float* qbase = Q + ((size_t)bh * SEQ + q0) * DIM;
        #pragma unroll
        for (int s = 0; s < 2; ++s)
            #pragma unroll
            for (int f = 0; f < 2; ++f) {
                const float* p = qbase + (s * 16 + col) * DIM + f * 32 + g * 8;
                qf[s][f] = cvt8(*(const f32x4*)p, *(const f32x4*)(p + 4));
            }
    }
    const float* mb = mask + (size_t)b * SEQ + kb;

    auto loadK = [&](int kt, f16x8& a, f16x8& c) {
        if (PRECONV) {
            const _Float16* kp = Kh + ((size_t)bh * SEQ + kb + kt * 16 + col) * DIM + g * 8;
            a = *(const f16x8*)kp;
            c = *(const f16x8*)(kp + 32);
        } else {
            const float* kp = K + ((size_t)bh * SEQ + kb + kt * 16 + col) * DIM + g * 8;
            a = cvt8(*(const f32x4*)kp,        *(const f32x4*)(kp + 4));
            c = cvt8(*(const f32x4*)(kp + 32), *(const f32x4*)(kp + 36));
        }
    };

    // ---- pass 1: partial row sums of exp(s)*mask
    float rsum[2] = {0.f, 0.f};
    {
        f16x8 k0, k1;
        loadK(0, k0, k1);
        f32x4 m4 = *(const f32x4*)(mb + g * 4);
        for (int kt = 0; kt < 32; ++kt) {
            int ktn = (kt + 1) & 31;
            f16x8 n0, n1;
            loadK(ktn, n0, n1);
            f32x4 nm = *(const f32x4*)(mb + ktn * 16 + g * 4);
            #pragma unroll
            for (int s = 0; s < 2; ++s) {
                f32x4 acc = {0.f, 0.f, 0.f, 0.f};
                acc = MFMA32(k0, qf[s][0], acc);
                acc = MFMA32(k1, qf[s][1], acc);
                rsum[s] += __expf(acc[0] * scale) * m4[0] + __expf(acc[1] * scale) * m4[1]
                         + __expf(acc[2] * scale) * m4[2] + __expf(acc[3] * scale) * m4[3];
            }
            k0 = n0; k1 = n1; m4 = nm;
        }
    }
    #pragma unroll
    for (int s = 0; s < 2; ++s) {
        float r = rsum[s];
        r += __shfl_xor(r, 16, 64);
        r += __shfl_xor(r, 32, 64);
        rsum[s] = r;
    }
    if (g == 0) {
        rs_lds[w][0][col] = rsum[0];
        rs_lds[w][1][col] = rsum[1];
    }
    __syncthreads();
    float inv[2];
    #pragma unroll
    for (int s = 0; s < 2; ++s)
        inv[s] = 1.0f / (rs_lds[pq * 2][s][col] + rs_lds[pq * 2 + 1][s][col] + 1e-8f);

    // ---- pass 2: recompute, normalize, stage scores in LDS, accumulate PV
    f32x4 cacc[2][4];
    #pragma unroll
    for (int s = 0; s < 2; ++s)
        #pragma unroll
        for (int dt = 0; dt < 4; ++dt) cacc[s][dt] = (f32x4){0.f, 0.f, 0.f, 0.f};

    float* srow0 = scores + ((size_t)bh * SEQ + q0) * SEQ + kb;
    const _Float16* vtb = VT + (size_t)bh * DIM * SEQ + kb;

    {
        f16x8 k0, k1;
        loadK(0, k0, k1);
        f32x4 m4 = *(const f32x4*)(mb + g * 4);
        for (int kt = 0; kt < 32; ++kt) {
            int ktn = (kt + 1) & 31;
            f16x8 n0, n1;
            loadK(ktn, n0, n1);
            f32x4 nm = *(const f32x4*)(mb + ktn * 16 + g * 4);
            const int ktl = kt & 3;

            f16x4 pf[2];
            #pragma unroll
            for (int s = 0; s < 2; ++s) {
                f32x4 acc = {0.f, 0.f, 0.f, 0.f};
                acc = MFMA32(k0, qf[s][0], acc);
                acc = MFMA32(k1, qf[s][1], acc);
                f32x4 p;
                p[0] = __expf(acc[0] * scale) * m4[0] * inv[s];
                p[1] = __expf(acc[1] * scale) * m4[1] * inv[s];
                p[2] = __expf(acc[2] * scale) * m4[2] * inv[s];
                p[3] = __expf(acc[3] * scale) * m4[3] * inv[s];
                // stage to LDS tile: row = s*16+col, granule (ktl*4+g) ^ (row&15)
                *(f32x4*)(wtile + (s * 16 + col) * 64 + (((ktl * 4 + g) ^ col) * 4)) = p;
                f16x4 ph;
                ph[0] = (_Float16)p[0]; ph[1] = (_Float16)p[1];
                ph[2] = (_Float16)p[2]; ph[3] = (_Float16)p[3];
                pf[s] = ph;
            }
            #pragma unroll
            for (int dt = 0; dt < 4; ++dt) {
                f16x4 vt;
                if (PRECONV) {
                    vt = *(const f16x4*)(vtb + ((size_t)(dt * 16 + col)) * SEQ + kt * 16 + g * 4);
                } else {
                    #pragma unroll
                    for (int i = 0; i < 4; ++i)
                        vt[i] = (_Float16)V[((size_t)bh * SEQ + kb + kt * 16 + g * 4 + i) * DIM + dt * 16 + col];
                }
                cacc[0][dt] = MFMA16(vt, pf[0], cacc[0][dt]);
                cacc[1][dt] = MFMA16(vt, pf[1], cacc[1][dt]);
            }

            // flush every 4 k-tiles: 8 wave stores of 4 rows x 256 B (full lines)
            if (ktl == 3) {
                float* sdst = srow0 + (kt >> 2) * 64 + col * 4;
                #pragma unroll
                for (int j = 0; j < 8; ++j) {
                    int row  = j * 4 + g;
                    int slot = col ^ (row & 15);
                    f32x4 vals = *(f32x4*)(wtile + row * 64 + slot * 4);
                    *(f32x4*)(sdst + (size_t)row * SEQ) = vals;
                }
            }
            k0 = n0; k1 = n1; m4 = nm;
        }
    }

    // ---- combine PV partials across the wave pair, store ctx
    __syncthreads();   // all flush reads done before cbuf aliases tiles 0-1
    float* cb = smem;  // cbuf[pq][e][lane] aliases waves 0-1 tiles (8192 floats)
    if (khf == 1) {
        #pragma unroll
        for (int s = 0; s < 2; ++s)
            #pragma unroll
            for (int dt = 0; dt < 4; ++dt)
                #pragma unroll
                for (int j = 0; j < 4; ++j)
                    cb[pq * 2048 + ((s * 4 + dt) * 4 + j) * 64 + lane] = cacc[s][dt][j];
    }
    __syncthreads();
    if (khf == 0) {
        #pragma unroll
        for (int s = 0; s < 2; ++s)
            #pragma unroll
            for (int dt = 0; dt < 4; ++dt) {
                f32x4 r = cacc[s][dt];
                #pragma unroll
                for (int j = 0; j < 4; ++j)
                    r[j] += cb[pq * 2048 + ((s * 4 + dt) * 4 + j) * 64 + lane];
                *(f32x4*)(ctx + ((size_t)bh * SEQ + q0 + s * 16 + col) * DIM + dt * 16 + g * 4) = r;
            }
    }
}

extern "C" void kernel_launch(void* const* d_in, const int* in_sizes, int n_in,
                              void* d_out, int out_size, void* d_ws, size_t ws_size,
                              hipStream_t stream)
{
    const float* Q    = (const float*)d_in[0];
    const float* K    = (const float*)d_in[1];
    const float* V    = (const float*)d_in[2];
    const float* mask = (const float*)d_in[3];
    float* ctx    = (float*)d_out;
    float* scores = ctx + (size_t)BHN * SEQ * DIM;

    const size_t elems = (size_t)BHN * SEQ * DIM;       // 4,194,304
    const size_t need  = elems * 2 * sizeof(_Float16);  // Kh + VT = 16 MB
    if (ws_size >= need) {
        _Float16* Kh = (_Float16*)d_ws;
        _Float16* VT = Kh + elems;
        cvt_kv<<<512, 256, 0, stream>>>(K, V, Kh, VT);
        attn_main<true><<<1024, 256, 0, stream>>>(Q, K, V, mask, Kh, VT, ctx, scores);
    } else {
        attn_main<false><<<1024, 256, 0, stream>>>(Q, K, V, mask, nullptr, nullptr, ctx, scores);
    }
}

// Round 4
// 135.133 us; speedup vs baseline: 1.2510x; 1.1701x over previous
//
#include <hip/hip_runtime.h>

// B=8,H=8,S=1024,D=64 fp32 attention, raw-exp softmax, multiplicative key mask.
// Outputs: context[64,1024,64] then scores[64,1024,1024], both fp32.
// R4: SINGLE pass. Block = 32 q-rows x 1024 keys, 4 waves (256-key quarters).
// E=exp(s)*mask staged f16 in 64 KB LDS tile; rowsums computed from the tile;
// scores written as full 4-KB contiguous rows with nontemporal stores (L2 bypass);
// PV accumulated unnormalized in registers, scaled by inv at the end.

typedef float    f32x4 __attribute__((ext_vector_type(4)));
typedef _Float16 f16x8 __attribute__((ext_vector_type(8)));
typedef _Float16 f16x4 __attribute__((ext_vector_type(4)));

#define MFMA32(A, B, C) __builtin_amdgcn_mfma_f32_16x16x32_f16((A), (B), (C), 0, 0, 0)
#define MFMA16(A, B, C) __builtin_amdgcn_mfma_f32_16x16x16f16((A), (B), (C), 0, 0, 0)

#define BHN 64
#define SEQ 1024
#define DIM 64

__device__ inline f16x8 cvt8(f32x4 a, f32x4 b) {
    f16x8 r;
    r[0] = (_Float16)a[0]; r[1] = (_Float16)a[1]; r[2] = (_Float16)a[2]; r[3] = (_Float16)a[3];
    r[4] = (_Float16)b[0]; r[5] = (_Float16)b[1]; r[6] = (_Float16)b[2]; r[7] = (_Float16)b[3];
    return r;
}

// Pre-pass: K -> f16 same layout; V -> f16 transposed per (b,h): VT[bh][d][key].
__global__ __launch_bounds__(256)
void cvt_kv(const float* __restrict__ K, const float* __restrict__ V,
            _Float16* __restrict__ Kh, _Float16* __restrict__ VT)
{
    __shared__ _Float16 tile[128 * 65];
    const int bh = blockIdx.x >> 3;
    const int kc = blockIdx.x & 7;
    const int t  = threadIdx.x;
    const size_t base = ((size_t)bh * SEQ + (size_t)kc * 128) * DIM;

    for (int it = 0; it < 8; ++it) {
        int idx = it * 256 + t;
        int key = idx >> 4;
        int c4  = idx & 15;
        f32x4 kv = *(const f32x4*)(K + base + key * DIM + c4 * 4);
        f32x4 vv = *(const f32x4*)(V + base + key * DIM + c4 * 4);
        f16x4 kh4;
        kh4[0] = (_Float16)kv[0]; kh4[1] = (_Float16)kv[1];
        kh4[2] = (_Float16)kv[2]; kh4[3] = (_Float16)kv[3];
        *(f16x4*)(Kh + base + key * DIM + c4 * 4) = kh4;
        tile[key * 65 + c4 * 4 + 0] = (_Float16)vv[0];
        tile[key * 65 + c4 * 4 + 1] = (_Float16)vv[1];
        tile[key * 65 + c4 * 4 + 2] = (_Float16)vv[2];
        tile[key * 65 + c4 * 4 + 3] = (_Float16)vv[3];
    }
    __syncthreads();
    for (int it = 0; it < 4; ++it) {
        int idx = it * 256 + t;
        int dd = idx >> 4;
        int kg = idx & 15;
        f16x8 o;
        #pragma unroll
        for (int j = 0; j < 8; ++j) o[j] = tile[(kg * 8 + j) * 65 + dd];
        *(f16x8*)(VT + ((size_t)bh * DIM + dd) * SEQ + (size_t)kc * 128 + kg * 8) = o;
    }
}

// Main kernel. 2048 blocks x 256 thr. Block = 32 q-rows of one (b,h), all keys.
// Wave w owns key quarter [w*256, w*256+256).
// Swapped QK^T: acc = mfma(A=K, B=Q) -> lane: qrow = lane&15, key = (lane>>4)*4+i.
// E-tile layout: row r (0..31) at byte r*2048; 8-B granule kg (4 keys), stored at
// kg ^ ((r&3)<<2) — XOR swizzle keeps granules intact, spreads banks.
template <bool PRECONV>
__global__ __launch_bounds__(256, 2)
void attn_main(const float* __restrict__ Q, const float* __restrict__ K,
               const float* __restrict__ V, const float* __restrict__ mask,
               const _Float16* __restrict__ Kh, const _Float16* __restrict__ VT,
               float* __restrict__ ctx, float* __restrict__ scores)
{
    __shared__ _Float16 Et[32 * 1024];   // 64 KB

    const int bid = blockIdx.x;
    const int wg  = ((bid & 7) << 8) | (bid >> 3);  // XCD-bijective (2048 % 8 == 0)
    const int bh  = wg >> 5;
    const int qb  = wg & 31;
    const int b   = bh >> 3;
    const int w    = threadIdx.x >> 6;   // key quarter
    const int lane = threadIdx.x & 63;
    const int col  = lane & 15;
    const int g    = lane >> 4;
    const int q0   = qb * 32;
    const int kb   = w * 256;
    const float scale = 0.125f;
    char* EtB = (char*)Et;

    // ---- Q fragments: qf[s][f] : Q[q0+s*16+col][f*32 + g*8 .. +7]
    f16x8 qf[2][2];
    {
        const float* qbase = Q + ((size_t)bh * SEQ + q0) * DIM;
        #pragma unroll
        for (int s = 0; s < 2; ++s)
            #pragma unroll
            for (int f = 0; f < 2; ++f) {
                const float* p = qbase + (s * 16 + col) * DIM + f * 32 + g * 8;
                qf[s][f] = cvt8(*(const f32x4*)p, *(const f32x4*)(p + 4));
            }
    }
    const float* mb = mask + (size_t)b * SEQ + kb;
    const _Float16* vtb = VT + (size_t)bh * DIM * SEQ + kb;

    // ---- single pass over this wave's 16 k-tiles
    f32x4 cacc[2][4];
    #pragma unroll
    for (int s = 0; s < 2; ++s)
        #pragma unroll
        for (int dt = 0; dt < 4; ++dt) cacc[s][dt] = (f32x4){0.f, 0.f, 0.f, 0.f};

    for (int kt = 0; kt < 16; ++kt) {
        f16x8 kf0, kf1;
        if (PRECONV) {
            const _Float16* kp = Kh + ((size_t)bh * SEQ + kb + kt * 16 + col) * DIM + g * 8;
            kf0 = *(const f16x8*)kp;
            kf1 = *(const f16x8*)(kp + 32);
        } else {
            const float* kp = K + ((size_t)bh * SEQ + kb + kt * 16 + col) * DIM + g * 8;
            kf0 = cvt8(*(const f32x4*)kp,        *(const f32x4*)(kp + 4));
            kf1 = cvt8(*(const f32x4*)(kp + 32), *(const f32x4*)(kp + 36));
        }
        f32x4 m4 = *(const f32x4*)(mb + kt * 16 + g * 4);

        f16x4 pf[2];
        #pragma unroll
        for (int s = 0; s < 2; ++s) {
            f32x4 acc = {0.f, 0.f, 0.f, 0.f};
            acc = MFMA32(kf0, qf[s][0], acc);
            acc = MFMA32(kf1, qf[s][1], acc);
            f16x4 eh;
            eh[0] = (_Float16)(__expf(acc[0] * scale) * m4[0]);
            eh[1] = (_Float16)(__expf(acc[1] * scale) * m4[1]);
            eh[2] = (_Float16)(__expf(acc[2] * scale) * m4[2]);
            eh[3] = (_Float16)(__expf(acc[3] * scale) * m4[3]);
            pf[s] = eh;
            const int row = s * 16 + col;
            const int kg  = (w * 64 + kt * 4 + g) ^ ((row & 3) << 2);
            *(f16x4*)(EtB + row * 2048 + kg * 8) = eh;
        }
        #pragma unroll
        for (int dt = 0; dt < 4; ++dt) {
            f16x4 vt;
            if (PRECONV) {
                vt = *(const f16x4*)(vtb + ((size_t)(dt * 16 + col)) * SEQ + kt * 16 + g * 4);
            } else {
                #pragma unroll
                for (int i = 0; i < 4; ++i)
                    vt[i] = (_Float16)V[((size_t)bh * SEQ + kb + kt * 16 + g * 4 + i) * DIM + dt * 16 + col];
            }
            cacc[0][dt] = MFMA16(vt, pf[0], cacc[0][dt]);
            cacc[1][dt] = MFMA16(vt, pf[1], cacc[1][dt]);
        }
    }

    __syncthreads();

    // ---- phase 3: wave w handles rows r0..r0+7: rowsum from tile, scale, write.
    // Lane l covers keys {q*256 + l*4 .. +3}, q=0..3 -> each store instr = 1 KB contig.
    const int r0 = w * 8;
    float* srow = scores + ((size_t)bh * SEQ + q0) * SEQ;
    for (int j = 0; j < 8; ++j) {
        const int r = r0 + j;
        f16x4 ev[4];
        #pragma unroll
        for (int q = 0; q < 4; ++q) {
            const int kg = (q * 64 + lane) ^ ((r & 3) << 2);
            ev[q] = *(const f16x4*)(EtB + r * 2048 + kg * 8);
        }
        float s0 = 0.f;
        #pragma unroll
        for (int q = 0; q < 4; ++q)
            #pragma unroll
            for (int i = 0; i < 4; ++i) s0 += (float)ev[q][i];
        #pragma unroll
        for (int off = 1; off < 64; off <<= 1) s0 += __shfl_xor(s0, off, 64);
        const float invr = 1.0f / (s0 + 1e-8f);
        float* dst = srow + (size_t)r * SEQ + lane * 4;
        #pragma unroll
        for (int q = 0; q < 4; ++q) {
            f32x4 o;
            o[0] = (float)ev[q][0] * invr;
            o[1] = (float)ev[q][1] * invr;
            o[2] = (float)ev[q][2] * invr;
            o[3] = (float)ev[q][3] * invr;
            __builtin_nontemporal_store(o, (f32x4*)(dst + q * 256));
        }
        // stash inv for the PV epilogue; row r0 was fully read at j==0 (this wave only)
        if (lane == 0) *(float*)(EtB + r0 * 2048 + j * 4) = invr;
    }

    __syncthreads();

    // ---- PV combine: waves 1..3 dump cacc into tile rows {1-4, 9-12, 17-20}
    // (avoids inv slots at rows 0/8/16/24 bytes 0..31). Wave 0 reduces + writes ctx.
    if (w != 0) {
        float* dump = (float*)(EtB + (1 + (w - 1) * 8) * 2048);
        #pragma unroll
        for (int s = 0; s < 2; ++s)
            #pragma unroll
            for (int dt = 0; dt < 4; ++dt)
                #pragma unroll
                for (int i = 0; i < 4; ++i)
                    dump[((s * 4 + dt) * 4 + i) * 64 + lane] = cacc[s][dt][i];
    }
    __syncthreads();
    if (w == 0) {
        #pragma unroll
        for (int s = 0; s < 2; ++s) {
            const int qrow = s * 16 + col;
            const float invr = *(const float*)(EtB + (qrow >> 3) * 8 * 2048 + (qrow & 7) * 4);
            #pragma unroll
            for (int dt = 0; dt < 4; ++dt) {
                f32x4 r = cacc[s][dt];
                #pragma unroll
                for (int ww = 1; ww < 4; ++ww) {
                    const float* dump = (const float*)(EtB + (1 + (ww - 1) * 8) * 2048);
                    #pragma unroll
                    for (int i = 0; i < 4; ++i)
                        r[i] += dump[((s * 4 + dt) * 4 + i) * 64 + lane];
                }
                r[0] *= invr; r[1] *= invr; r[2] *= invr; r[3] *= invr;
                *(f32x4*)(ctx + ((size_t)bh * SEQ + q0 + qrow) * DIM + dt * 16 + g * 4) = r;
            }
        }
    }
}

extern "C" void kernel_launch(void* const* d_in, const int* in_sizes, int n_in,
                              void* d_out, int out_size, void* d_ws, size_t ws_size,
                              hipStream_t stream)
{
    const float* Q    = (const float*)d_in[0];
    const float* K    = (const float*)d_in[1];
    const float* V    = (const float*)d_in[2];
    const float* mask = (const float*)d_in[3];
    float* ctx    = (float*)d_out;
    float* scores = ctx + (size_t)BHN * SEQ * DIM;

    const size_t elems = (size_t)BHN * SEQ * DIM;       // 4,194,304
    const size_t need  = elems * 2 * sizeof(_Float16);  // Kh + VT = 16 MB
    if (ws_size >= need) {
        _Float16* Kh = (_Float16*)d_ws;
        _Float16* VT = Kh + elems;
        cvt_kv<<<512, 256, 0, stream>>>(K, V, Kh, VT);
        attn_main<true><<<2048, 256, 0, stream>>>(Q, K, V, mask, Kh, VT, ctx, scores);
    } else {
        attn_main<false><<<2048, 256, 0, stream>>>(Q, K, V, mask, nullptr, nullptr, ctx, scores);
    }
}